// Round 2
// baseline (676.056 us; speedup 1.0000x reference)
//
#include <hip/hip_runtime.h>

#define NN   100000
#define NE   1600000
#define DIM  128
#define NBKT 391                  // ceil(NN/256) buckets of 256 nodes
#define EPB  16384                // edges per binning block
#define NBLK 98                   // ceil(NE/EPB)
#define NTILES (NN / 16)          // 6250 node-tiles of 16 rows
#define CASTB 12500               // cast_x blocks (NN*DIM/4/256)
#define CWB   384                 // castw blocks (3*128*256/256)

// ---- XCD-sliced feature layout: feat[slice][node][16 dims], slice = dim>>4 ----
// slice = blockIdx%8 == XCD id (measured round-robin dispatch) -> each XCD's
// gather working set is its own 3.2 MB slice, resident in its 4 MB L2.
#define NSLC 8
#define GCH  512                  // nodes per gather block
#define GATB (((NN + GCH - 1) / GCH) * NSLC)   // 196*8 = 1568

typedef short          s16x8 __attribute__((ext_vector_type(8)));
typedef unsigned short u16x8 __attribute__((ext_vector_type(8)));
typedef float          f32x4 __attribute__((ext_vector_type(4)));

__device__ __forceinline__ unsigned short f2b(float f) {
    unsigned u = __float_as_uint(f);
    unsigned r = ((u >> 16) & 1u) + 0x7FFFu;   // RNE
    return (unsigned short)((u + r) >> 16);
}
__device__ __forceinline__ float b2f(unsigned short h) {
    return __uint_as_float(((unsigned)h) << 16);
}

// ---- fused prep: [0,NBLK) hist | [NBLK,NBLK+CASTB) cast_x | rest castw ----
__global__ void k_prep(const float* __restrict__ x, unsigned short* __restrict__ xb,
                       const int* __restrict__ dst, int* __restrict__ hist,
                       const float* __restrict__ W1l, const float* __restrict__ W1r,
                       const float* __restrict__ W2l, const float* __restrict__ W2r,
                       const float* __restrict__ W3l, const float* __restrict__ W3r,
                       unsigned short* __restrict__ Wt1, unsigned short* __restrict__ Wt2,
                       unsigned short* __restrict__ Wt3) {
    __shared__ int lh[NBKT];
    int t = threadIdx.x, b = blockIdx.x;
    if (b < NBLK) {
        // bucket histogram -> hist[k*NBLK + b] (bucket-major)
        for (int j = t; j < NBKT; j += 256) lh[j] = 0;
        __syncthreads();
        int base = b * EPB;
        int end = base + EPB; if (end > NE) end = NE;
        for (int i = base + t; i < end; i += 256) atomicAdd(&lh[dst[i] >> 8], 1);
        __syncthreads();
        for (int j = t; j < NBKT; j += 256) hist[j * NBLK + b] = lh[j];
    } else if (b < NBLK + CASTB) {
        // fp32 -> bf16 feature cast, output in sliced layout (write-coalesced:
        // i is the OUTPUT ushort4 index; reads are 64B-segment gathers from x)
        int i = (b - NBLK) * 256 + t;          // 3.2M ushort4 outputs
        int slice = i / (NN * 4);              // const-div -> magic mul
        int rem = i - slice * (NN * 4);
        int node = rem >> 2;
        int off4 = i & 3;                      // rem&3 == i&3 (400000 % 4 == 0)
        float4 v = ((const float4*)x)[node * 32 + slice * 4 + off4];
        ushort4 o;
        o.x = f2b(v.x); o.y = f2b(v.y); o.z = f2b(v.z); o.w = f2b(v.w);
        ((ushort4*)xb)[i] = o;
    } else {
        // weight cast: Wt[n][k] = bf16( k<128 ? Wl[k][n] : Wr[k-128][n] )
        int i = (b - NBLK - CASTB) * 256 + t;   // 3 * 128 * 256
        int L = i >> 15;
        int rem = i & 32767;
        int n = rem >> 8;
        int k = rem & 255;
        const float* Wl = (L == 0) ? W1l : (L == 1) ? W2l : W3l;
        const float* Wr = (L == 0) ? W1r : (L == 1) ? W2r : W3r;
        unsigned short* Wt = (L == 0) ? Wt1 : (L == 1) ? Wt2 : Wt3;
        float v = (k < 128) ? Wl[k * 128 + n] : Wr[(k - 128) * 128 + n];
        Wt[n * 256 + k] = f2b(v);
    }
}

// ---- phase 2a: per-bucket row scan (exclusive over the 98 block counts) ----
__global__ void k_scanrow(int* __restrict__ hist, int* __restrict__ row_total) {
    __shared__ int sh[128];
    int k = blockIdx.x, t = threadIdx.x;
    int v = (t < NBLK) ? hist[k * NBLK + t] : 0;
    sh[t] = v;
    __syncthreads();
    for (int off = 1; off < 128; off <<= 1) {
        int a = (t >= off) ? sh[t - off] : 0;
        __syncthreads();
        sh[t] += a;
        __syncthreads();
    }
    if (t < NBLK) hist[k * NBLK + t] = sh[t] - v;   // exclusive within row
    if (t == 127) row_total[k] = sh[127];
}

// ---- phase 2b: exclusive scan of 391 bucket totals, single block ----
__global__ void k_scanbkt(const int* __restrict__ row_total, int* __restrict__ bbase) {
    __shared__ int sh[512];
    int t = threadIdx.x;
    int v = (t < NBKT) ? row_total[t] : 0;
    sh[t] = v;
    __syncthreads();
    for (int off = 1; off < 512; off <<= 1) {
        int a = (t >= off) ? sh[t - off] : 0;
        __syncthreads();
        sh[t] += a;
        __syncthreads();
    }
    if (t < NBKT) bbase[t] = sh[t] - v;
    if (t == NBKT) bbase[NBKT] = NE;
}

// ---- phase 3: bin edges deterministically: word = (src<<8)|(dst&255) ----
__global__ void k_bin2(const int* __restrict__ src, const int* __restrict__ dst,
                       const int* __restrict__ hist, const int* __restrict__ bbase,
                       int* __restrict__ binned) {
    __shared__ int s_base[NBKT];
    __shared__ int s_cnt[NBKT];
    int t = threadIdx.x, b = blockIdx.x;
    for (int j = t; j < NBKT; j += 256) {
        s_base[j] = bbase[j] + hist[j * NBLK + b];
        s_cnt[j] = 0;
    }
    __syncthreads();
    int base = b * EPB;
    int end = base + EPB; if (end > NE) end = NE;
    for (int i = base + t; i < end; i += 256) {
        int d = dst[i];
        int k = d >> 8;
        int w = (src[i] << 8) | (d & 255);
        int lpos = atomicAdd(&s_cnt[k], 1);
        binned[s_base[k] + lpos] = w;
    }
}

// ---- per-bucket CSR build: LDS degree hist + scan + staged coalesced write ----
__global__ void k_build(const int* __restrict__ binned,
                        const int* __restrict__ bucket_base,
                        int* __restrict__ csr,
                        int* __restrict__ row_start,
                        float* __restrict__ deg_inv) {
    __shared__ int s_deg[256], s_scan[256], s_cur[256];
    __shared__ int stage[8192];
    int b = blockIdx.x, t = threadIdx.x;
    int base = bucket_base[b], end = bucket_base[b + 1];
    int cnt = end - base;
    s_deg[t] = 0;
    __syncthreads();
    for (int i = t; i < cnt; i += 256)
        atomicAdd(&s_deg[binned[base + i] & 255], 1);
    __syncthreads();
    s_scan[t] = s_deg[t];
    __syncthreads();
    for (int off = 1; off < 256; off <<= 1) {
        int a = (t >= off) ? s_scan[t - off] : 0;
        __syncthreads();
        s_scan[t] += a;
        __syncthreads();
    }
    int excl = s_scan[t] - s_deg[t];
    s_cur[t] = excl;
    int node = b * 256 + t;
    if (node < NN) {
        int d = s_deg[t];
        row_start[node] = base + excl;
        deg_inv[node]   = (d > 0) ? 1.0f / (float)d : 0.0f;
    }
    if (b == 0 && t == 0) row_start[NN] = NE;   // sentinel: deg = rs[n+1]-rs[n]
    __syncthreads();
    for (int i = t; i < cnt; i += 256) {
        int w = binned[base + i];           // L2-hot second read
        int pos = atomicAdd(&s_cur[w & 255], 1);
        int s = w >> 8;
        if (pos < 8192) stage[pos] = s;
        else            csr[base + pos] = s;   // overflow fallback (not expected)
    }
    __syncthreads();
    int m = cnt < 8192 ? cnt : 8192;
    for (int i = t; i < m; i += 256) csr[base + i] = stage[i];
}

// ---- mean aggregation, XCD-sliced: block (slice=b&7, chunk=b>>3) gathers only
// dims [slice*16, slice*16+16) of all its nodes.  slice table = 3.2 MB bf16 ->
// L2-resident per XCD (b%8 == XCD id, round-robin dispatch).  Per wave:
// 8 nodes x 4 neighbor-slots x 2 16B-chunks; 2-level shuffle reduce over slots.
// csr/meta streamed with nontemporal hints so they don't evict the slice.
__global__ void k_gather(const unsigned short* __restrict__ feat,
                         const int* __restrict__ row_start,
                         const float* __restrict__ deg_inv, const int* __restrict__ csr,
                         unsigned short* __restrict__ mean) {
    int b = blockIdx.x;
    int slice = b & (NSLC - 1);
    int chunk = b >> 3;
    int n0 = chunk * GCH;
    int n1 = n0 + GCH; if (n1 > NN) n1 = NN;
    int lane = threadIdx.x & 63;
    int wv   = threadIdx.x >> 6;
    int nsub = lane >> 3;              // node within octet (0..7)
    int q    = (lane >> 1) & 3;        // neighbor slot (0..3)
    int c    = lane & 1;               // 16B chunk within 32B slice-row
    const u16x8* fp = ((const u16x8*)feat) + (size_t)slice * (NN * 2);
    u16x8*       mp = ((u16x8*)mean)  + (size_t)slice * (NN * 2);
    for (int bn = n0 + wv * 8; bn < n1; bn += 32) {
        int n = bn + nsub;
        if (n >= n1) continue;         // never splits an octet (chunks % 32 == 0)
        int rs = __builtin_nontemporal_load(&row_start[n]);
        int re = __builtin_nontemporal_load(&row_start[n + 1]);
        int d = re - rs;
        float acc0[8], acc1[8];
#pragma unroll
        for (int t = 0; t < 8; t++) { acc0[t] = 0.0f; acc1[t] = 0.0f; }
        int j = q;
        for (; j + 4 < d; j += 8) {
            int s0 = __builtin_nontemporal_load(&csr[rs + j]);
            int s1 = __builtin_nontemporal_load(&csr[rs + j + 4]);
            u16x8 v0 = fp[s0 * 2 + c];
            u16x8 v1 = fp[s1 * 2 + c];
#pragma unroll
            for (int t = 0; t < 8; t++) { acc0[t] += b2f(v0[t]); acc1[t] += b2f(v1[t]); }
        }
        if (j < d) {
            int s0 = __builtin_nontemporal_load(&csr[rs + j]);
            u16x8 v0 = fp[s0 * 2 + c];
#pragma unroll
            for (int t = 0; t < 8; t++) acc0[t] += b2f(v0[t]);
        }
#pragma unroll
        for (int t = 0; t < 8; t++) acc0[t] += acc1[t];
#pragma unroll
        for (int t = 0; t < 8; t++) {       // reduce over q (lane bits 1-2)
            acc0[t] += __shfl_xor(acc0[t], 2, 64);
            acc0[t] += __shfl_xor(acc0[t], 4, 64);
        }
        if (q == 0) {
            float s = __builtin_nontemporal_load(&deg_inv[n]);
            u16x8 o;
#pragma unroll
            for (int t = 0; t < 8; t++) o[t] = f2b(acc0[t] * s);
            __builtin_nontemporal_store(o, &mp[n * 2 + c]);   // 256B/wave dense
        }
    }
}

// ---- fused linear v4: LDS weights as MFMA *A*-operand; sliced B inputs ----
// acc = mfma(W_frag, X_frag): col(lane&15)=node, row(quad*4+r)=outdim.
// B-load from sliced layout: k-chunk kc=kt*4+q -> slice kc>>1, half kc&1
// (2 contiguous 512B segments per load instr).  MODE 0 stores sliced bf16
// (dense 512B segment per instr); MODE 1 stores dense fp32 rows (final out).
template <int MODE>
__global__ void __launch_bounds__(512)
k_lin(const unsigned short* __restrict__ meanb,
      const unsigned short* __restrict__ hb,
      const unsigned short* __restrict__ Wt,
      const float* __restrict__ bias, void* __restrict__ out) {
    __shared__ s16x8 sW[4096];             // 64 KB
    int t = threadIdx.x;
    const s16x8* wp = (const s16x8*)Wt;
    // stage in fragment order: chunk ci -> frag (ci>>6), lane (ci&63)
    // A-frag for tile (mt,kt): m = mt*16 + (lane&15), k-chunk = kt*4 + (lane>>4)
#pragma unroll
    for (int it = 0; it < 8; it++) {
        int ci = it * 512 + t;
        int frag = ci >> 6, ln = ci & 63;
        int mt = frag >> 3, kt = frag & 7;
        int m = mt * 16 + (ln & 15);
        int kc = kt * 4 + (ln >> 4);
        sW[ci] = wp[m * 32 + kc];
    }
    __syncthreads();

    int lane = t & 63;
    int wv   = t >> 6;
    int tile = blockIdx.x * 8 + wv;        // node tile (16 nodes)
    if (tile >= NTILES) return;
    int n0 = tile * 16;
    int q = lane >> 4, c = lane & 15;
    const s16x8* mp = (const s16x8*)meanb;
    const s16x8* hp = (const s16x8*)hb;
    int row = n0 + c;                      // B: n(node) = lane&15
    s16x8 B[8];
#pragma unroll
    for (int kt = 0; kt < 4; kt++) {
        int kc = kt * 4 + q;
        B[kt] = mp[((kc >> 1) * NN + row) * 2 + (kc & 1)];
    }
#pragma unroll
    for (int kt = 0; kt < 4; kt++) {
        int kc = kt * 4 + q;
        B[4 + kt] = hp[((kc >> 1) * NN + row) * 2 + (kc & 1)];
    }
    const f32x4* bp = (const f32x4*)bias;
#pragma unroll
    for (int mt = 0; mt < 8; mt++) {
        f32x4 acc = {0.f, 0.f, 0.f, 0.f};
#pragma unroll
        for (int kt = 0; kt < 8; kt++)
            acc = __builtin_amdgcn_mfma_f32_16x16x32_bf16(sW[(mt * 8 + kt) * 64 + lane],
                                                          B[kt], acc, 0, 0, 0);
        f32x4 bv = bp[mt * 4 + q];         // outdims mt*16+q*4 .. +3
        int node = n0 + c;
        if (MODE == 0) {
            ushort4 o;
            float v0 = acc[0] + bv[0]; if (v0 < 0.f) v0 = 0.f;
            float v1 = acc[1] + bv[1]; if (v1 < 0.f) v1 = 0.f;
            float v2 = acc[2] + bv[2]; if (v2 < 0.f) v2 = 0.f;
            float v3 = acc[3] + bv[3]; if (v3 < 0.f) v3 = 0.f;
            o.x = f2b(v0); o.y = f2b(v1); o.z = f2b(v2); o.w = f2b(v3);
            ((ushort4*)out)[(mt * NN + node) * 4 + q] = o;   // sliced: slice=mt
        } else {
            f32x4 v;
#pragma unroll
            for (int r = 0; r < 4; r++) v[r] = acc[r] + bv[r];
            ((f32x4*)out)[node * 32 + mt * 4 + q] = v;       // dense fp32 rows
        }
    }
}

extern "C" void kernel_launch(void* const* d_in, const int* in_sizes, int n_in,
                              void* d_out, int out_size, void* d_ws, size_t ws_size,
                              hipStream_t stream) {
    const float* x   = (const float*)d_in[1];
    const int*   ei  = (const int*)d_in[2];
    const int*   src = ei;
    const int*   dst = ei + NE;
    const float* W1l = (const float*)d_in[3];
    const float* W1r = (const float*)d_in[4];
    const float* b1  = (const float*)d_in[5];
    const float* W2l = (const float*)d_in[6];
    const float* W2r = (const float*)d_in[7];
    const float* b2  = (const float*)d_in[8];
    const float* W3l = (const float*)d_in[9];
    const float* W3r = (const float*)d_in[10];
    const float* b3  = (const float*)d_in[11];

    // workspace carve (all 256B aligned)
    char* w = (char*)d_ws;
    auto carve = [&](size_t bytes) {
        void* p = (void*)w;
        w += (bytes + 255) & ~(size_t)255;
        return p;
    };
    int*   row_start = (int*)carve((NN + 1) * 4);
    float* deg_inv   = (float*)carve(NN * 4);
    int*   hist      = (int*)carve((size_t)NBKT * NBLK * 4);
    int*   row_total = (int*)carve(NBKT * 4);
    int*   bbase     = (int*)carve((NBKT + 1) * 4);
    int*   csr       = (int*)carve((size_t)NE * 4);
    unsigned short* Wt1 = (unsigned short*)carve(128 * 256 * 2);
    unsigned short* Wt2 = (unsigned short*)carve(128 * 256 * 2);
    unsigned short* Wt3 = (unsigned short*)carve(128 * 256 * 2);
    unsigned short* xb    = (unsigned short*)carve((size_t)NN * DIM * 2);
    unsigned short* meanb = (unsigned short*)carve((size_t)NN * DIM * 2);
    unsigned short* h1b   = (unsigned short*)carve((size_t)NN * DIM * 2);
    unsigned short* h2b   = xb;          // x dead after layer-2 B-load
    int*   binned    = (int*)meanb;      // binned (6.4 MB) dead before first k_gather

    k_prep<<<NBLK + CASTB + CWB, 256, 0, stream>>>(x, xb, dst, hist,
                                                   W1l, W1r, W2l, W2r, W3l, W3r,
                                                   Wt1, Wt2, Wt3);
    k_scanrow<<<NBKT, 128, 0, stream>>>(hist, row_total);
    k_scanbkt<<<1, 512, 0, stream>>>(row_total, bbase);
    k_bin2<<<NBLK, 256, 0, stream>>>(src, dst, hist, bbase, binned);
    k_build<<<NBKT, 256, 0, stream>>>(binned, bbase, csr, row_start, deg_inv);

    const int LB = (NTILES + 7) / 8;        // k_lin blocks (8 waves = 8 tiles each)

    // layer 1: mean over xb -> h1 = relu(lin)
    k_gather<<<GATB, 256, 0, stream>>>(xb, row_start, deg_inv, csr, meanb);
    k_lin<0><<<LB, 512, 0, stream>>>(meanb, xb, Wt1, b1, (void*)h1b);
    // layer 2: mean over h1 -> h2 = relu(lin)
    k_gather<<<GATB, 256, 0, stream>>>(h1b, row_start, deg_inv, csr, meanb);
    k_lin<0><<<LB, 512, 0, stream>>>(meanb, h1b, Wt2, b2, (void*)h2b);
    // layer 3: mean over h2 -> dx_dt (fp32, no activation)
    k_gather<<<GATB, 256, 0, stream>>>(h2b, row_start, deg_inv, csr, meanb);
    k_lin<1><<<LB, 512, 0, stream>>>(meanb, h2b, Wt3, b3, d_out);
}

// Round 3
// 511.285 us; speedup vs baseline: 1.3223x; 1.3223x over previous
//
#include <hip/hip_runtime.h>

#define NN   100000
#define NE   1600000
#define DIM  128
#define NBKT 391                  // ceil(NN/256) buckets of 256 nodes
#define EPB  16384                // edges per binning block
#define NBLK 98                   // ceil(NE/EPB)
#define NTILES (NN / 16)          // 6250 node-tiles of 16 rows
#define CASTB 12500               // cast_x blocks (NN*DIM/4/256)
#define CWB   384                 // castw blocks (3*128*256/256)

// ---- XCD-sliced feature layout: feat[slice][node][16 dims], slice = dim>>4 ----
// slice = blockIdx%8 == XCD id (round-robin dispatch) -> each XCD's gather
// working set is its own 3.2 MB slice, resident in its 4 MB L2.
// R2 lesson: FETCH 181->69 MB proved residency works; the 2.3x slowdown was
// the nontemporal csr loads (chain-head went 94% L2-hit -> 100% miss). NO nt.
#define NSLC 8
#define GCH  512                  // nodes per gather block
#define GATB (((NN + GCH - 1) / GCH) * NSLC)   // 196*8 = 1568

typedef short          s16x8 __attribute__((ext_vector_type(8)));
typedef unsigned short u16x8 __attribute__((ext_vector_type(8)));
typedef float          f32x4 __attribute__((ext_vector_type(4)));

__device__ __forceinline__ unsigned short f2b(float f) {
    unsigned u = __float_as_uint(f);
    unsigned r = ((u >> 16) & 1u) + 0x7FFFu;   // RNE
    return (unsigned short)((u + r) >> 16);
}
__device__ __forceinline__ float b2f(unsigned short h) {
    return __uint_as_float(((unsigned)h) << 16);
}

// ---- fused prep: [0,NBLK) hist | [NBLK,NBLK+CASTB) cast_x | rest castw ----
__global__ void k_prep(const float* __restrict__ x, unsigned short* __restrict__ xb,
                       const int* __restrict__ dst, int* __restrict__ hist,
                       const float* __restrict__ W1l, const float* __restrict__ W1r,
                       const float* __restrict__ W2l, const float* __restrict__ W2r,
                       const float* __restrict__ W3l, const float* __restrict__ W3r,
                       unsigned short* __restrict__ Wt1, unsigned short* __restrict__ Wt2,
                       unsigned short* __restrict__ Wt3) {
    __shared__ int lh[NBKT];
    int t = threadIdx.x, b = blockIdx.x;
    if (b < NBLK) {
        // bucket histogram -> hist[k*NBLK + b] (bucket-major)
        for (int j = t; j < NBKT; j += 256) lh[j] = 0;
        __syncthreads();
        int base = b * EPB;
        int end = base + EPB; if (end > NE) end = NE;
        for (int i = base + t; i < end; i += 256) atomicAdd(&lh[dst[i] >> 8], 1);
        __syncthreads();
        for (int j = t; j < NBKT; j += 256) hist[j * NBLK + b] = lh[j];
    } else if (b < NBLK + CASTB) {
        // fp32 -> bf16 feature cast, output in sliced layout (write-coalesced:
        // i is the OUTPUT ushort4 index; reads are 64B-segment gathers from x)
        int i = (b - NBLK) * 256 + t;          // 3.2M ushort4 outputs
        int slice = i / (NN * 4);              // const-div -> magic mul
        int rem = i - slice * (NN * 4);
        int node = rem >> 2;
        int off4 = i & 3;                      // rem&3 == i&3 (400000 % 4 == 0)
        float4 v = ((const float4*)x)[node * 32 + slice * 4 + off4];
        ushort4 o;
        o.x = f2b(v.x); o.y = f2b(v.y); o.z = f2b(v.z); o.w = f2b(v.w);
        ((ushort4*)xb)[i] = o;
    } else {
        // weight cast: Wt[n][k] = bf16( k<128 ? Wl[k][n] : Wr[k-128][n] )
        int i = (b - NBLK - CASTB) * 256 + t;   // 3 * 128 * 256
        int L = i >> 15;
        int rem = i & 32767;
        int n = rem >> 8;
        int k = rem & 255;
        const float* Wl = (L == 0) ? W1l : (L == 1) ? W2l : W3l;
        const float* Wr = (L == 0) ? W1r : (L == 1) ? W2r : W3r;
        unsigned short* Wt = (L == 0) ? Wt1 : (L == 1) ? Wt2 : Wt3;
        float v = (k < 128) ? Wl[k * 128 + n] : Wr[(k - 128) * 128 + n];
        Wt[n * 256 + k] = f2b(v);
    }
}

// ---- phase 2a: per-bucket row scan (exclusive over the 98 block counts) ----
__global__ void k_scanrow(int* __restrict__ hist, int* __restrict__ row_total) {
    __shared__ int sh[128];
    int k = blockIdx.x, t = threadIdx.x;
    int v = (t < NBLK) ? hist[k * NBLK + t] : 0;
    sh[t] = v;
    __syncthreads();
    for (int off = 1; off < 128; off <<= 1) {
        int a = (t >= off) ? sh[t - off] : 0;
        __syncthreads();
        sh[t] += a;
        __syncthreads();
    }
    if (t < NBLK) hist[k * NBLK + t] = sh[t] - v;   // exclusive within row
    if (t == 127) row_total[k] = sh[127];
}

// ---- phase 2b: exclusive scan of 391 bucket totals, single block ----
__global__ void k_scanbkt(const int* __restrict__ row_total, int* __restrict__ bbase) {
    __shared__ int sh[512];
    int t = threadIdx.x;
    int v = (t < NBKT) ? row_total[t] : 0;
    sh[t] = v;
    __syncthreads();
    for (int off = 1; off < 512; off <<= 1) {
        int a = (t >= off) ? sh[t - off] : 0;
        __syncthreads();
        sh[t] += a;
        __syncthreads();
    }
    if (t < NBKT) bbase[t] = sh[t] - v;
    if (t == NBKT) bbase[NBKT] = NE;
}

// ---- phase 3: bin edges deterministically: word = (src<<8)|(dst&255) ----
__global__ void k_bin2(const int* __restrict__ src, const int* __restrict__ dst,
                       const int* __restrict__ hist, const int* __restrict__ bbase,
                       int* __restrict__ binned) {
    __shared__ int s_base[NBKT];
    __shared__ int s_cnt[NBKT];
    int t = threadIdx.x, b = blockIdx.x;
    for (int j = t; j < NBKT; j += 256) {
        s_base[j] = bbase[j] + hist[j * NBLK + b];
        s_cnt[j] = 0;
    }
    __syncthreads();
    int base = b * EPB;
    int end = base + EPB; if (end > NE) end = NE;
    for (int i = base + t; i < end; i += 256) {
        int d = dst[i];
        int k = d >> 8;
        int w = (src[i] << 8) | (d & 255);
        int lpos = atomicAdd(&s_cnt[k], 1);
        binned[s_base[k] + lpos] = w;
    }
}

// ---- per-bucket CSR build: LDS degree hist + scan + staged coalesced write ----
__global__ void k_build(const int* __restrict__ binned,
                        const int* __restrict__ bucket_base,
                        int* __restrict__ csr,
                        int* __restrict__ row_start,
                        float* __restrict__ deg_inv) {
    __shared__ int s_deg[256], s_scan[256], s_cur[256];
    __shared__ int stage[8192];
    int b = blockIdx.x, t = threadIdx.x;
    int base = bucket_base[b], end = bucket_base[b + 1];
    int cnt = end - base;
    s_deg[t] = 0;
    __syncthreads();
    for (int i = t; i < cnt; i += 256)
        atomicAdd(&s_deg[binned[base + i] & 255], 1);
    __syncthreads();
    s_scan[t] = s_deg[t];
    __syncthreads();
    for (int off = 1; off < 256; off <<= 1) {
        int a = (t >= off) ? s_scan[t - off] : 0;
        __syncthreads();
        s_scan[t] += a;
        __syncthreads();
    }
    int excl = s_scan[t] - s_deg[t];
    s_cur[t] = excl;
    int node = b * 256 + t;
    if (node < NN) {
        int d = s_deg[t];
        row_start[node] = base + excl;
        deg_inv[node]   = (d > 0) ? 1.0f / (float)d : 0.0f;
    }
    if (b == 0 && t == 0) row_start[NN] = NE;   // sentinel: deg = rs[n+1]-rs[n]
    __syncthreads();
    for (int i = t; i < cnt; i += 256) {
        int w = binned[base + i];           // L2-hot second read
        int pos = atomicAdd(&s_cur[w & 255], 1);
        int s = w >> 8;
        if (pos < 8192) stage[pos] = s;
        else            csr[base + pos] = s;   // overflow fallback (not expected)
    }
    __syncthreads();
    int m = cnt < 8192 ? cnt : 8192;
    for (int i = t; i < m; i += 256) csr[base + i] = stage[i];
}

// ---- mean aggregation, XCD-sliced: block (slice=b&7, chunk=b>>3) gathers only
// dims [slice*16, slice*16+16) of all its nodes.  slice table = 3.2 MB bf16 ->
// L2-resident per XCD.  Per wave: 8 nodes x 4 neighbor-slots x 2 16B-chunks;
// 2-level shuffle reduce over slots.  All loads NORMAL (cached): csr is the
// chain head -- it must L2-hit (R2: nt on csr cost 2.3x).
__global__ void k_gather(const unsigned short* __restrict__ feat,
                         const int* __restrict__ row_start,
                         const float* __restrict__ deg_inv, const int* __restrict__ csr,
                         unsigned short* __restrict__ mean) {
    int b = blockIdx.x;
    int slice = b & (NSLC - 1);
    int chunk = b >> 3;
    int n0 = chunk * GCH;
    int n1 = n0 + GCH; if (n1 > NN) n1 = NN;
    int lane = threadIdx.x & 63;
    int wv   = threadIdx.x >> 6;
    int nsub = lane >> 3;              // node within octet (0..7)
    int q    = (lane >> 1) & 3;        // neighbor slot (0..3)
    int c    = lane & 1;               // 16B chunk within 32B slice-row
    const u16x8* fp = ((const u16x8*)feat) + (size_t)slice * (NN * 2);
    u16x8*       mp = ((u16x8*)mean)  + (size_t)slice * (NN * 2);
    for (int bn = n0 + wv * 8; bn < n1; bn += 32) {
        int n = bn + nsub;
        if (n >= n1) continue;         // never splits an octet (chunks % 32 == 0)
        int rs = row_start[n];
        int re = row_start[n + 1];
        int d = re - rs;
        float acc0[8], acc1[8];
#pragma unroll
        for (int t = 0; t < 8; t++) { acc0[t] = 0.0f; acc1[t] = 0.0f; }
        int j = q;
        for (; j + 4 < d; j += 8) {
            int s0 = csr[rs + j];
            int s1 = csr[rs + j + 4];
            u16x8 v0 = fp[s0 * 2 + c];
            u16x8 v1 = fp[s1 * 2 + c];
#pragma unroll
            for (int t = 0; t < 8; t++) { acc0[t] += b2f(v0[t]); acc1[t] += b2f(v1[t]); }
        }
        if (j < d) {
            int s0 = csr[rs + j];
            u16x8 v0 = fp[s0 * 2 + c];
#pragma unroll
            for (int t = 0; t < 8; t++) acc0[t] += b2f(v0[t]);
        }
#pragma unroll
        for (int t = 0; t < 8; t++) acc0[t] += acc1[t];
#pragma unroll
        for (int t = 0; t < 8; t++) {       // reduce over q (lane bits 1-2)
            acc0[t] += __shfl_xor(acc0[t], 2, 64);
            acc0[t] += __shfl_xor(acc0[t], 4, 64);
        }
        if (q == 0) {
            float s = deg_inv[n];
            u16x8 o;
#pragma unroll
            for (int t = 0; t < 8; t++) o[t] = f2b(acc0[t] * s);
            mp[n * 2 + c] = o;              // 256B/wave dense
        }
    }
}

// ---- fused linear v4: LDS weights as MFMA *A*-operand; sliced B inputs ----
// acc = mfma(W_frag, X_frag): col(lane&15)=node, row(quad*4+r)=outdim.
// B-load from sliced layout: k-chunk kc=kt*4+q -> slice kc>>1, half kc&1
// (2 contiguous 512B segments per load instr).  MODE 0 stores sliced bf16
// (dense 512B segment per instr); MODE 1 stores dense fp32 rows (final out).
template <int MODE>
__global__ void __launch_bounds__(512)
k_lin(const unsigned short* __restrict__ meanb,
      const unsigned short* __restrict__ hb,
      const unsigned short* __restrict__ Wt,
      const float* __restrict__ bias, void* __restrict__ out) {
    __shared__ s16x8 sW[4096];             // 64 KB
    int t = threadIdx.x;
    const s16x8* wp = (const s16x8*)Wt;
    // stage in fragment order: chunk ci -> frag (ci>>6), lane (ci&63)
    // A-frag for tile (mt,kt): m = mt*16 + (lane&15), k-chunk = kt*4 + (lane>>4)
#pragma unroll
    for (int it = 0; it < 8; it++) {
        int ci = it * 512 + t;
        int frag = ci >> 6, ln = ci & 63;
        int mt = frag >> 3, kt = frag & 7;
        int m = mt * 16 + (ln & 15);
        int kc = kt * 4 + (ln >> 4);
        sW[ci] = wp[m * 32 + kc];
    }
    __syncthreads();

    int lane = t & 63;
    int wv   = t >> 6;
    int tile = blockIdx.x * 8 + wv;        // node tile (16 nodes)
    if (tile >= NTILES) return;
    int n0 = tile * 16;
    int q = lane >> 4, c = lane & 15;
    const s16x8* mp = (const s16x8*)meanb;
    const s16x8* hp = (const s16x8*)hb;
    int row = n0 + c;                      // B: n(node) = lane&15
    s16x8 B[8];
#pragma unroll
    for (int kt = 0; kt < 4; kt++) {
        int kc = kt * 4 + q;
        B[kt] = mp[((kc >> 1) * NN + row) * 2 + (kc & 1)];
    }
#pragma unroll
    for (int kt = 0; kt < 4; kt++) {
        int kc = kt * 4 + q;
        B[4 + kt] = hp[((kc >> 1) * NN + row) * 2 + (kc & 1)];
    }
    const f32x4* bp = (const f32x4*)bias;
#pragma unroll
    for (int mt = 0; mt < 8; mt++) {
        f32x4 acc = {0.f, 0.f, 0.f, 0.f};
#pragma unroll
        for (int kt = 0; kt < 8; kt++)
            acc = __builtin_amdgcn_mfma_f32_16x16x32_bf16(sW[(mt * 8 + kt) * 64 + lane],
                                                          B[kt], acc, 0, 0, 0);
        f32x4 bv = bp[mt * 4 + q];         // outdims mt*16+q*4 .. +3
        int node = n0 + c;
        if (MODE == 0) {
            ushort4 o;
            float v0 = acc[0] + bv[0]; if (v0 < 0.f) v0 = 0.f;
            float v1 = acc[1] + bv[1]; if (v1 < 0.f) v1 = 0.f;
            float v2 = acc[2] + bv[2]; if (v2 < 0.f) v2 = 0.f;
            float v3 = acc[3] + bv[3]; if (v3 < 0.f) v3 = 0.f;
            o.x = f2b(v0); o.y = f2b(v1); o.z = f2b(v2); o.w = f2b(v3);
            ((ushort4*)out)[(mt * NN + node) * 4 + q] = o;   // sliced: slice=mt
        } else {
            f32x4 v;
#pragma unroll
            for (int r = 0; r < 4; r++) v[r] = acc[r] + bv[r];
            ((f32x4*)out)[node * 32 + mt * 4 + q] = v;       // dense fp32 rows
        }
    }
}

extern "C" void kernel_launch(void* const* d_in, const int* in_sizes, int n_in,
                              void* d_out, int out_size, void* d_ws, size_t ws_size,
                              hipStream_t stream) {
    const float* x   = (const float*)d_in[1];
    const int*   ei  = (const int*)d_in[2];
    const int*   src = ei;
    const int*   dst = ei + NE;
    const float* W1l = (const float*)d_in[3];
    const float* W1r = (const float*)d_in[4];
    const float* b1  = (const float*)d_in[5];
    const float* W2l = (const float*)d_in[6];
    const float* W2r = (const float*)d_in[7];
    const float* b2  = (const float*)d_in[8];
    const float* W3l = (const float*)d_in[9];
    const float* W3r = (const float*)d_in[10];
    const float* b3  = (const float*)d_in[11];

    // workspace carve (all 256B aligned)
    char* w = (char*)d_ws;
    auto carve = [&](size_t bytes) {
        void* p = (void*)w;
        w += (bytes + 255) & ~(size_t)255;
        return p;
    };
    int*   row_start = (int*)carve((NN + 1) * 4);
    float* deg_inv   = (float*)carve(NN * 4);
    int*   hist      = (int*)carve((size_t)NBKT * NBLK * 4);
    int*   row_total = (int*)carve(NBKT * 4);
    int*   bbase     = (int*)carve((NBKT + 1) * 4);
    int*   csr       = (int*)carve((size_t)NE * 4);
    unsigned short* Wt1 = (unsigned short*)carve(128 * 256 * 2);
    unsigned short* Wt2 = (unsigned short*)carve(128 * 256 * 2);
    unsigned short* Wt3 = (unsigned short*)carve(128 * 256 * 2);
    unsigned short* xb    = (unsigned short*)carve((size_t)NN * DIM * 2);
    unsigned short* meanb = (unsigned short*)carve((size_t)NN * DIM * 2);
    unsigned short* h1b   = (unsigned short*)carve((size_t)NN * DIM * 2);
    unsigned short* h2b   = xb;          // x dead after layer-2 B-load
    int*   binned    = (int*)meanb;      // binned (6.4 MB) dead before first k_gather

    k_prep<<<NBLK + CASTB + CWB, 256, 0, stream>>>(x, xb, dst, hist,
                                                   W1l, W1r, W2l, W2r, W3l, W3r,
                                                   Wt1, Wt2, Wt3);
    k_scanrow<<<NBKT, 128, 0, stream>>>(hist, row_total);
    k_scanbkt<<<1, 512, 0, stream>>>(row_total, bbase);
    k_bin2<<<NBLK, 256, 0, stream>>>(src, dst, hist, bbase, binned);
    k_build<<<NBKT, 256, 0, stream>>>(binned, bbase, csr, row_start, deg_inv);

    const int LB = (NTILES + 7) / 8;        // k_lin blocks (8 waves = 8 tiles each)

    // layer 1: mean over xb -> h1 = relu(lin)
    k_gather<<<GATB, 256, 0, stream>>>(xb, row_start, deg_inv, csr, meanb);
    k_lin<0><<<LB, 512, 0, stream>>>(meanb, xb, Wt1, b1, (void*)h1b);
    // layer 2: mean over h1 -> h2 = relu(lin)
    k_gather<<<GATB, 256, 0, stream>>>(h1b, row_start, deg_inv, csr, meanb);
    k_lin<0><<<LB, 512, 0, stream>>>(meanb, h1b, Wt2, b2, (void*)h2b);
    // layer 3: mean over h2 -> dx_dt (fp32, no activation)
    k_gather<<<GATB, 256, 0, stream>>>(h2b, row_start, deg_inv, csr, meanb);
    k_lin<1><<<LB, 512, 0, stream>>>(meanb, h2b, Wt3, b3, d_out);
}